// Round 7
// baseline (1928.251 us; speedup 1.0000x reference)
//
#include <hip/hip_runtime.h>
#include <math.h>

#define M_ROWS 2048
#define N_KEYS 65536
#define DKK 512
#define DVV 512
#define KTOP 32
#define NSPLIT 16
#define NRANGE (N_KEYS / NSPLIT)   // 4096
#define BM 128
#define BN 128
#define MBLKS (M_ROWS / BM)        // 16
#define NTILES (NRANGE / BN)       // 32
#define KSTEPS (DKK / 32)          // 16
#define TOT (NTILES * KSTEPS)      // 512
#define CAP 16
#define CSTR 17
#define TILE_E 4096                // elements per 128x32 tile

typedef _Float16 f16x8 __attribute__((ext_vector_type(8)));
typedef float f32x4 __attribute__((ext_vector_type(4)));

// ===================== FAST PATH =====================

// norm + f16 hi/lo split + TILED+SWIZZLED layout:
// array[blk][ks][128x32], elem (rr,oct) stored at [rr*32 + (oct^((rr>>1)&3))*8]
__global__ void __launch_bounds__(256) norm_split_kernel(
    const float* __restrict__ q, const float* __restrict__ keys,
    _Float16* __restrict__ QhT, _Float16* __restrict__ QlT,
    _Float16* __restrict__ KhT, _Float16* __restrict__ KlT) {
  const int gw = (blockIdx.x * 256 + threadIdx.x) >> 6;
  const int lane = threadIdx.x & 63;
  const float* row; _Float16 *oh, *ol; int rr;
  if (gw < M_ROWS) {
    row = q + (size_t)gw * DKK; rr = gw & 127;
    const size_t tb = (size_t)(gw >> 7) * 16 * TILE_E;
    oh = QhT + tb; ol = QlT + tb;
  } else {
    const int n = gw - M_ROWS;
    if (n >= N_KEYS) return;
    row = keys + (size_t)n * DKK; rr = n & 127;
    const size_t tb = (size_t)(n >> 7) * 16 * TILE_E;
    oh = KhT + tb; ol = KlT + tb;
  }
  const float4 a = *(const float4*)&row[lane * 8];
  const float4 b = *(const float4*)&row[lane * 8 + 4];
  float s = a.x*a.x + a.y*a.y + a.z*a.z + a.w*a.w
          + b.x*b.x + b.y*b.y + b.z*b.z + b.w*b.w;
#pragma unroll
  for (int off = 32; off; off >>= 1) s += __shfl_xor(s, off);
  const float inv = 1.0f / fmaxf(sqrtf(s), 1e-12f);

  f16x8 h, l;
  const float e[8] = {a.x, a.y, a.z, a.w, b.x, b.y, b.z, b.w};
#pragma unroll
  for (int j = 0; j < 8; ++j) {
    const float y = e[j] * inv;
    h[j] = (_Float16)y;
    l[j] = (_Float16)(y - (float)h[j]);
  }
  const int ks = lane >> 2, oct = lane & 3;
  const int po = oct ^ ((rr >> 1) & 3);
  const size_t off = (size_t)ks * TILE_E + rr * 32 + po * 8;
  *(f16x8*)&oh[off] = h;
  *(f16x8*)&ol[off] = l;
}

__device__ __forceinline__ void insert32(float* tS, int* tI, float s, int idx) {
  const float ms = tS[31]; const int mi_ = tI[31];
  if (s < ms || (s == ms && idx > mi_)) return;
  int p = 0;
  while (p < KTOP && (tS[p] > s || (tS[p] == s && tI[p] < idx))) ++p;
  for (int qq = KTOP - 1; qq > p; --qq) { tS[qq] = tS[qq-1]; tI[qq] = tI[qq-1]; }
  tS[p] = s; tI[p] = idx;
}

__device__ __forceinline__ void gll16(const _Float16* g, _Float16* l) {
  __builtin_amdgcn_global_load_lds(
      (const __attribute__((address_space(1))) void*)g,
      (__attribute__((address_space(3))) void*)l, 16, 0, 0);
}

#define SQL(i) sQl##i
#define SKH(i) sKh##i
#define SKL(i) sKl##i

// stage one K-step tile set (Ql,Kh,Kl; each 8KB contiguous) into buffer B
#define STAGE(B, KB, KS2) do {                                         \
  gll16(QlT + qlb + (size_t)(KS2) * TILE_E, &SQL(B)[ldsA]);            \
  gll16(KhT + (KB) + (size_t)(KS2) * TILE_E, &SKH(B)[ldsA]);           \
  gll16(KlT + (KB) + (size_t)(KS2) * TILE_E, &SKL(B)[ldsA]);           \
} while (0)

#define KBAR(NVM) do {                                                 \
  __builtin_amdgcn_sched_barrier(0);                                   \
  asm volatile("s_waitcnt vmcnt(" #NVM ")" ::: "memory");              \
  __builtin_amdgcn_sched_barrier(0);                                   \
  __builtin_amdgcn_s_barrier();                                        \
  __builtin_amdgcn_sched_barrier(0);                                   \
} while (0)

#define LBAR() do {                                                    \
  __builtin_amdgcn_sched_barrier(0);                                   \
  asm volatile("s_waitcnt lgkmcnt(0)" ::: "memory");                   \
  __builtin_amdgcn_sched_barrier(0);                                   \
  __builtin_amdgcn_s_barrier();                                        \
  __builtin_amdgcn_sched_barrier(0);                                   \
} while (0)

// one K-step: wait(oldest stage) -> barrier -> stage s+3 -> ds_read -> 24 MFMA
#define ONESTEP(KS, RB, SB) do {                                       \
  if (lastct && (KS) == 14) { KBAR(3); }                               \
  else if (lastct && (KS) == 15) { KBAR(0); }                          \
  else { KBAR(6); }                                                    \
  if ((KS) < 13) { STAGE(SB, kb, (KS) + 3); }                          \
  else if (!lastct) { STAGE(SB, kb + 16 * TILE_E, (KS) - 13); }        \
  f16x8 Al_[2], Bh_[4], Bl_[4];                                        \
  Al_[0] = *(const f16x8*)&SQL(RB)[offA[0]];                           \
  Al_[1] = *(const f16x8*)&SQL(RB)[offA[1]];                           \
  _Pragma("unroll")                                                    \
  for (int ni = 0; ni < 4; ++ni) {                                     \
    Bh_[ni] = *(const f16x8*)&SKH(RB)[offB[ni]];                       \
    Bl_[ni] = *(const f16x8*)&SKL(RB)[offB[ni]];                       \
  }                                                                    \
  __builtin_amdgcn_s_setprio(1);                                       \
  _Pragma("unroll")                                                    \
  for (int mi = 0; mi < 2; ++mi) {                                     \
    const f16x8 qa = (mi == 0) ? qh0[KS] : qh1[KS];                    \
    _Pragma("unroll")                                                  \
    for (int ni = 0; ni < 4; ++ni) {                                   \
      acc[mi][ni] = __builtin_amdgcn_mfma_f32_16x16x32_f16(Al_[mi], Bh_[ni], acc[mi][ni], 0, 0, 0); \
      acc[mi][ni] = __builtin_amdgcn_mfma_f32_16x16x32_f16(qa, Bl_[ni], acc[mi][ni], 0, 0, 0);      \
      acc[mi][ni] = __builtin_amdgcn_mfma_f32_16x16x32_f16(qa, Bh_[ni], acc[mi][ni], 0, 0, 0);      \
    }                                                                  \
  }                                                                    \
  __builtin_amdgcn_s_setprio(0);                                       \
} while (0)

__global__ void __launch_bounds__(512, 2) gemm_topk_kernel(
    const _Float16* __restrict__ QhT, const _Float16* __restrict__ QlT,
    const _Float16* __restrict__ KhT, const _Float16* __restrict__ KlT,
    float* __restrict__ pscore, int* __restrict__ pidx) {
  // 12 DISTINCT shared objects -> compiler can prove gll/ds_read no-alias
  __shared__ __attribute__((aligned(16))) _Float16 sQl0[TILE_E], sQl1[TILE_E], sQl2[TILE_E], sQl3[TILE_E];
  __shared__ __attribute__((aligned(16))) _Float16 sKh0[TILE_E], sKh1[TILE_E], sKh2[TILE_E], sKh3[TILE_E];
  __shared__ __attribute__((aligned(16))) _Float16 sKl0[TILE_E], sKl1[TILE_E], sKl2[TILE_E], sKl3[TILE_E];
  __shared__ float topS[BM * 33];
  __shared__ int   topI[BM * 33];
  __shared__ float candS[BM * CSTR];
  __shared__ int   candI[BM * CSTR];
  __shared__ float mS[BM];
  __shared__ int   cnt[BM];
  __shared__ int   sOver;

  const int tid  = threadIdx.x;
  const int lane = tid & 63;
  const int w    = tid >> 6;           // 8 waves
  const int wr   = w >> 1, wc = w & 1; // wave tile 32x64
  const int cl   = lane & 15;
  const int g    = lane >> 4;
  const int g4   = g * 4;

  // XCD-chunked bijective swizzle: 256 blocks = 8 XCD * 32
  const int lin   = (int)(blockIdx.x + gridDim.x * blockIdx.y);
  const int virt  = (lin & 7) * 32 + (lin >> 3);
  const int mblk  = virt & (MBLKS - 1);
  const int split = virt >> 4;
  const int qbase  = mblk * BM;
  const int nbase0 = split * NRANGE;

  const int ldsA = tid * 8;                       // linear LDS staging slot
  const size_t qlb = (size_t)mblk * 16 * TILE_E + ldsA;
  const size_t kb0 = (size_t)(split * NTILES) * 16 * TILE_E + ldsA;

  // fragment offsets (tile-image swizzle)
  int offA[2], offB[4];
#pragma unroll
  for (int mi = 0; mi < 2; ++mi) {
    const int r = wr * 32 + mi * 16 + cl;
    offA[mi] = r * 32 + (g ^ ((r >> 1) & 3)) * 8;
  }
#pragma unroll
  for (int ni = 0; ni < 4; ++ni) {
    const int c = wc * 64 + ni * 16 + cl;
    offB[ni] = c * 32 + (g ^ ((c >> 1) & 3)) * 8;
  }

  // Qh fragments live in registers (tile-invariant): 32 x f16x8 = 128 VGPR
  f16x8 qh0[16], qh1[16];
  {
    const size_t qhb = (size_t)mblk * 16 * TILE_E;
#pragma unroll
    for (int ks = 0; ks < 16; ++ks) {
      qh0[ks] = *(const f16x8*)&QhT[qhb + (size_t)ks * TILE_E + offA[0]];
      qh1[ks] = *(const f16x8*)&QhT[qhb + (size_t)ks * TILE_E + offA[1]];
    }
  }

  if (tid < BM) {
    mS[tid] = -INFINITY; cnt[tid] = 0;
#pragma unroll
    for (int j = 0; j < KTOP; ++j) { topS[tid*33+j] = -INFINITY; topI[tid*33+j] = 0x7fffffff; }
  }
  if (tid == 0) sOver = 0;

  // prologue: 3 stages in flight
  STAGE(0, kb0, 0);
  STAGE(1, kb0, 1);
  STAGE(2, kb0, 2);

  for (int ct = 0; ct < NTILES; ++ct) {
    const bool lastct = (ct == NTILES - 1);
    const size_t kb = kb0 + (size_t)ct * 16 * TILE_E;
    const int n0 = nbase0 + ct * BN;
    f32x4 acc[2][4];
#pragma unroll
    for (int mi = 0; mi < 2; ++mi)
#pragma unroll
      for (int ni = 0; ni < 4; ++ni) acc[mi][ni] = (f32x4)0.0f;

    ONESTEP(0, 0, 3);  ONESTEP(1, 1, 0);  ONESTEP(2, 2, 1);  ONESTEP(3, 3, 2);
    ONESTEP(4, 0, 3);  ONESTEP(5, 1, 0);  ONESTEP(6, 2, 1);  ONESTEP(7, 3, 2);
    ONESTEP(8, 0, 3);  ONESTEP(9, 1, 0);  ONESTEP(10, 2, 1); ONESTEP(11, 3, 2);
    ONESTEP(12, 0, 3); ONESTEP(13, 1, 0); ONESTEP(14, 2, 1); ONESTEP(15, 3, 2);

    // -------- candidate scan from accumulators (vmcnt NOT drained) --------
    LBAR();
    float m[2][4];
#pragma unroll
    for (int mi = 0; mi < 2; ++mi) {
      const f32x4 mv = *(const f32x4*)&mS[wr * 32 + mi * 16 + g4];
      m[mi][0] = mv[0]; m[mi][1] = mv[1]; m[mi][2] = mv[2]; m[mi][3] = mv[3];
    }
    unsigned int pend = 0u;
#pragma unroll
    for (int mi = 0; mi < 2; ++mi)
#pragma unroll
      for (int ni = 0; ni < 4; ++ni)
#pragma unroll
        for (int j = 0; j < 4; ++j)
          if (acc[mi][ni][j] >= m[mi][j])
            pend |= 1u << (mi * 16 + ni * 4 + j);

    for (;;) {
      if (pend) {
#pragma unroll
        for (int mi = 0; mi < 2; ++mi)
#pragma unroll
          for (int ni = 0; ni < 4; ++ni)
#pragma unroll
            for (int j = 0; j < 4; ++j) {
              const int bit = mi * 16 + ni * 4 + j;
              if (pend & (1u << bit)) {
                const int r = wr * 32 + mi * 16 + g4 + j;
                const int t = atomicAdd(&cnt[r], 1);
                if (t < CAP) {
                  candS[r * CSTR + t] = acc[mi][ni][j];
                  candI[r * CSTR + t] = n0 + wc * 64 + ni * 16 + cl;
                  pend &= ~(1u << bit);
                }
              }
            }
      }
      LBAR();
      if (tid < BM) {
        int nc = cnt[tid];
        if (nc > CAP) { sOver = 1; nc = CAP; }
        float* tS = &topS[tid * 33];
        int*   tI = &topI[tid * 33];
        for (int e = 0; e < nc; ++e) insert32(tS, tI, candS[tid * CSTR + e], candI[tid * CSTR + e]);
        mS[tid] = tS[KTOP - 1];
        cnt[tid] = 0;
      }
      LBAR();
      const int over = sOver;
      LBAR();
      if (tid == 0) sOver = 0;
      if (!over) break;
#pragma unroll
      for (int mi = 0; mi < 2; ++mi) {
        const f32x4 mv = *(const f32x4*)&mS[wr * 32 + mi * 16 + g4];
        m[mi][0] = mv[0]; m[mi][1] = mv[1]; m[mi][2] = mv[2]; m[mi][3] = mv[3];
      }
      unsigned int keep = 0u;
#pragma unroll
      for (int mi = 0; mi < 2; ++mi)
#pragma unroll
        for (int ni = 0; ni < 4; ++ni)
#pragma unroll
          for (int j = 0; j < 4; ++j) {
            const int bit = mi * 16 + ni * 4 + j;
            if ((pend & (1u << bit)) && acc[mi][ni][j] >= m[mi][j])
              keep |= 1u << bit;
          }
      pend = keep;
    }
  }

  if (tid < BM) {
    const size_t base = ((size_t)(qbase + tid) * NSPLIT + split) * KTOP;
    for (int j = 0; j < KTOP; ++j) {
      pscore[base + j] = topS[tid * 33 + j];
      pidx[base + j]   = topI[tid * 33 + j];
    }
  }
}

// ===================== FALLBACK (round-1, proven) =====================

#define QB 128
#define NB 128
#define KC 32
#define FNTILES (NRANGE / NB)
#define KCH (DKK / KC)
#define LDST 132

__global__ void __launch_bounds__(256) norm_kernel(
    const float* __restrict__ q, const float* __restrict__ keys,
    float* __restrict__ qn, float* __restrict__ kinv) {
  const int gw = (blockIdx.x * 256 + threadIdx.x) >> 6;
  const int lane = threadIdx.x & 63;
  if (gw < M_ROWS) {
    const float* row = q + (size_t)gw * DKK;
    float4 a = ((const float4*)row)[lane];
    float4 b = ((const float4*)row)[lane + 64];
    float s = a.x*a.x + a.y*a.y + a.z*a.z + a.w*a.w
            + b.x*b.x + b.y*b.y + b.z*b.z + b.w*b.w;
#pragma unroll
    for (int off = 32; off; off >>= 1) s += __shfl_xor(s, off);
    const float inv = 1.0f / fmaxf(sqrtf(s), 1e-12f);
    float* orow = qn + (size_t)gw * DKK;
    ((float4*)orow)[lane]      = make_float4(a.x*inv, a.y*inv, a.z*inv, a.w*inv);
    ((float4*)orow)[lane + 64] = make_float4(b.x*inv, b.y*inv, b.z*inv, b.w*inv);
  } else {
    const int n = gw - M_ROWS;
    if (n < N_KEYS) {
      const float* row = keys + (size_t)n * DKK;
      float4 a = ((const float4*)row)[lane];
      float4 b = ((const float4*)row)[lane + 64];
      float s = a.x*a.x + a.y*a.y + a.z*a.z + a.w*a.w
              + b.x*b.x + b.y*b.y + b.z*b.z + b.w*b.w;
#pragma unroll
      for (int off = 32; off; off >>= 1) s += __shfl_xor(s, off);
      if (lane == 0) kinv[n] = 1.0f / fmaxf(sqrtf(s), 1e-12f);
    }
  }
}

__device__ __forceinline__ void lds_wr_tile(float* dst, int k8, int r, float4 v, float scale) {
  dst[(k8 * 4 + 0) * LDST + r] = v.x * scale;
  dst[(k8 * 4 + 1) * LDST + r] = v.y * scale;
  dst[(k8 * 4 + 2) * LDST + r] = v.z * scale;
  dst[(k8 * 4 + 3) * LDST + r] = v.w * scale;
}

__global__ void __launch_bounds__(256, 1) score_topk_kernel(
    const float* __restrict__ qn, const float* __restrict__ keys,
    const float* __restrict__ kinv,
    float* __restrict__ pscore, int* __restrict__ pidx) {
  __shared__ float u[16896];
  __shared__ float topS[QB * KTOP];
  __shared__ int   topI[QB * KTOP];

  const int tid = threadIdx.x;
  const int tx = tid & 15, ty = tid >> 4;
  const int qbase = blockIdx.y * QB;
  const int nbase0 = blockIdx.x * NRANGE;

  for (int i = tid; i < QB * KTOP; i += 256) { topS[i] = -INFINITY; topI[i] = 0; }
  __syncthreads();

  for (int t = 0; t < FNTILES; ++t) {
    const int n0 = nbase0 + t * NB;
    float acc[8][8];
#pragma unroll
    for (int i = 0; i < 8; ++i)
#pragma unroll
      for (int j = 0; j < 8; ++j) acc[i][j] = 0.0f;

#pragma unroll
    for (int p = 0; p < 4; ++p) {
      const int id = tid + p * 256;
      const int r = id >> 3, k8 = id & 7;
      const float4 va = *(const float4*)&qn[(size_t)(qbase + r) * DKK + k8 * 4];
      const float4 vb = *(const float4*)&keys[(size_t)(n0 + r) * DKK + k8 * 4];
      const float kv = kinv[n0 + r];
      lds_wr_tile(u, k8, r, va, 1.0f);
      lds_wr_tile(u + 4224, k8, r, vb, kv);
    }
    __syncthreads();

    for (int kc = 0; kc < KCH; ++kc) {
      float4 pa[4], pb[4]; float pk[4];
      const bool pre = (kc + 1 < KCH);
      if (pre) {
#pragma unroll
        for (int p = 0; p < 4; ++p) {
          const int id = tid + p * 256;
          const int r = id >> 3, k8 = id & 7;
          pa[p] = *(const float4*)&qn[(size_t)(qbase + r) * DKK + (kc + 1) * KC + k8 * 4];
          pb[p] = *(const float4*)&keys[(size_t)(n0 + r) * DKK + (kc + 1) * KC + k8 * 4];
          pk[p] = kinv[n0 + r];
        }
      }
      const float* As = u + (kc & 1) * 8448;
      const float* Bs = As + 4224;
#pragma unroll 4
      for (int kk = 0; kk < KC; ++kk) {
        const float4 a0 = *(const float4*)&As[kk * LDST + ty * 4];
        const float4 a1 = *(const float4*)&As[kk * LDST + ty * 4 + 64];
        const float4 b0 = *(const float4*)&Bs[kk * LDST + tx * 4];
        const float4 b1 = *(const float4*)&Bs[kk * LDST + tx * 4 + 64];
        const float av[8] = {a0.x,a0.y,a0.z,a0.w,a1.x,a1.y,a1.z,a1.w};
        const float bv[8] = {b0.x,b0.y,b0.z,b0.w,b1.x,b1.y,b1.z,b1.w};
#pragma unroll
        for (int i = 0; i < 8; ++i)
#pragma unroll
          for (int j = 0; j < 8; ++j)
            acc[i][j] = fmaf(av[i], bv[j], acc[i][j]);
      }
      if (pre) {
        float* Ad = u + ((kc + 1) & 1) * 8448;
        float* Bd = Ad + 4224;
#pragma unroll
        for (int p = 0; p < 4; ++p) {
          const int id = tid + p * 256;
          const int r = id >> 3, k8 = id & 7;
          lds_wr_tile(Ad, k8, r, pa[p], 1.0f);
          lds_wr_tile(Bd, k8, r, pb[p], pk[p]);
        }
      }
      __syncthreads();
    }

#pragma unroll
    for (int ib = 0; ib < 2; ++ib)
#pragma unroll
      for (int i = 0; i < 4; ++i) {
        const int r = ty * 4 + i + ib * 64;
#pragma unroll
        for (int jb = 0; jb < 2; ++jb) {
          *(float4*)&u[r * LDST + tx * 4 + jb * 64] =
              make_float4(acc[ib*4+i][jb*4+0], acc[ib*4+i][jb*4+1],
                          acc[ib*4+i][jb*4+2], acc[ib*4+i][jb*4+3]);
        }
      }
    __syncthreads();

    if (tid < QB) {
      const int row = tid;
      float* tS = &topS[row * KTOP];
      int*   tI = &topI[row * KTOP];
      float mSv = tS[KTOP - 1]; int mIv = tI[KTOP - 1];
      for (int c4 = 0; c4 < NB / 4; ++c4) {
        const float4 v = *(const float4*)&u[row * LDST + c4 * 4];
#pragma unroll
        for (int wv = 0; wv < 4; ++wv) {
          const float s = (&v.x)[wv];
          const int idx = n0 + c4 * 4 + wv;
          if (s > mSv || (s == mSv && idx < mIv)) {
            int p = 0;
            while (p < KTOP && (tS[p] > s || (tS[p] == s && tI[p] < idx))) ++p;
            for (int qq = KTOP - 1; qq > p; --qq) { tS[qq] = tS[qq-1]; tI[qq] = tI[qq-1]; }
            tS[p] = s; tI[p] = idx;
            mSv = tS[KTOP - 1]; mIv = tI[KTOP - 1];
          }
        }
      }
    }
    __syncthreads();
  }

  if (tid < QB) {
    const size_t base = ((size_t)(qbase + tid) * NSPLIT + blockIdx.x) * KTOP;
    for (int j = 0; j < KTOP; ++j) {
      pscore[base + j] = topS[tid * KTOP + j];
      pidx[base + j]   = topI[tid * KTOP + j];
    }
  }
}

// ---------- shared: merge sorted partial lists, softmax, gather ----------
__global__ void __launch_bounds__(256) merge_kernel(
    const float* __restrict__ pscore, const int* __restrict__ pidx,
    const float* __restrict__ values,
    float* __restrict__ out_agg, float* __restrict__ out_attn, float* __restrict__ out_idx) {
  __shared__ float attn_s[KTOP];
  __shared__ int   sel_i[KTOP];
  const int row = blockIdx.x;
  const int tid = threadIdx.x;

  if (tid < 64) {
    const int lane = tid;
    const float* ps = pscore + (size_t)row * NSPLIT * KTOP;
    const int*   pi = pidx   + (size_t)row * NSPLIT * KTOP;
    int pos = 0;
    float s; int idx;
    if (lane < NSPLIT) { s = ps[lane * KTOP]; idx = pi[lane * KTOP]; }
    else { s = -INFINITY; idx = 0x7fffffff; }
    for (int it = 0; it < KTOP; ++it) {
      float wsv = s; int wi = idx; int wl = lane;
#pragma unroll
      for (int off = 32; off; off >>= 1) {
        const float os = __shfl_xor(wsv, off);
        const int   oi = __shfl_xor(wi, off);
        const int   ol = __shfl_xor(wl, off);
        if (os > wsv || (os == wsv && oi < wi)) { wsv = os; wi = oi; wl = ol; }
      }
      if (lane == 0) { attn_s[it] = wsv; sel_i[it] = wi; }
      if (lane == wl) {
        ++pos;
        if (pos < KTOP) { s = ps[lane * KTOP + pos]; idx = pi[lane * KTOP + pos]; }
        else { s = -INFINITY; idx = 0x7fffffff; }
      }
    }
  }
  __syncthreads();
  if (tid < KTOP) {
    const float mm = attn_s[0];
    const float e = expf((attn_s[tid] - mm) * 10.0f);
    float tsum = e;
#pragma unroll
    for (int off = 16; off; off >>= 1) tsum += __shfl_xor(tsum, off);
    const float a = e / tsum;
    out_attn[(size_t)row * KTOP + tid] = a;
    out_idx [(size_t)row * KTOP + tid] = (float)sel_i[tid];
    attn_s[tid] = a;
  }
  __syncthreads();

  const int d = tid * 2;
  float2 accv = make_float2(0.0f, 0.0f);
  for (int j = 0; j < KTOP; ++j) {
    const float wgt = attn_s[j];
    const float2 v = *(const float2*)&values[(size_t)sel_i[j] * DVV + d];
    accv.x = fmaf(wgt, v.x, accv.x);
    accv.y = fmaf(wgt, v.y, accv.y);
  }
  *(float2*)&out_agg[(size_t)row * DVV + d] = accv;
}

extern "C" void kernel_launch(void* const* d_in, const int* in_sizes, int n_in,
                              void* d_out, int out_size, void* d_ws, size_t ws_size,
                              hipStream_t stream) {
  const float* q      = (const float*)d_in[0];
  const float* keys   = (const float*)d_in[1];
  const float* values = (const float*)d_in[2];

  float* out      = (float*)d_out;
  float* out_agg  = out;
  float* out_attn = out + (size_t)M_ROWS * DVV;
  float* out_idx  = out_attn + (size_t)M_ROWS * KTOP;

  const size_t needFast =
      (size_t)M_ROWS * DKK * 2 * 2
    + (size_t)N_KEYS * DKK * 2 * 2
    + (size_t)M_ROWS * NSPLIT * KTOP * 8;

  if (ws_size >= needFast) {
    _Float16* QhT = (_Float16*)d_ws;
    _Float16* QlT = QhT + (size_t)M_ROWS * DKK;
    _Float16* KhT = QlT + (size_t)M_ROWS * DKK;
    _Float16* KlT = KhT + (size_t)N_KEYS * DKK;
    float* pscore = (float*)(KlT + (size_t)N_KEYS * DKK);
    int*   pidx   = (int*)(pscore + (size_t)M_ROWS * NSPLIT * KTOP);

    norm_split_kernel<<<(M_ROWS + N_KEYS) / 4, 256, 0, stream>>>(q, keys, QhT, QlT, KhT, KlT);
    dim3 g2(MBLKS, NSPLIT, 1);
    gemm_topk_kernel<<<g2, 512, 0, stream>>>(QhT, QlT, KhT, KlT, pscore, pidx);
    merge_kernel<<<M_ROWS, 256, 0, stream>>>(pscore, pidx, values, out_agg, out_attn, out_idx);
  } else {
    float* ws     = (float*)d_ws;
    float* qn     = ws;
    float* kinv   = qn + (size_t)M_ROWS * DKK;
    float* pscore = kinv + N_KEYS;
    int*   pidx   = (int*)(pscore + (size_t)M_ROWS * NSPLIT * KTOP);

    norm_kernel<<<(M_ROWS + N_KEYS) / 4, 256, 0, stream>>>(q, keys, qn, kinv);
    dim3 g2(NSPLIT, M_ROWS / QB, 1);
    score_topk_kernel<<<g2, 256, 0, stream>>>(qn, keys, kinv, pscore, pidx);
    merge_kernel<<<M_ROWS, 256, 0, stream>>>(pscore, pidx, values, out_agg, out_attn, out_idx);
  }
}

// Round 8
// 1703.886 us; speedup vs baseline: 1.1317x; 1.1317x over previous
//
#include <hip/hip_runtime.h>
#include <math.h>

#define M_ROWS 2048
#define N_KEYS 65536
#define DKK 512
#define DVV 512
#define KTOP 32
#define NSPLIT 16
#define NRANGE (N_KEYS / NSPLIT)   // 4096
#define BM 128
#define BN 128
#define MBLKS (M_ROWS / BM)        // 16
#define NTILES (NRANGE / BN)       // 32
#define KSTEPS (DKK / 32)          // 16
#define TOT (NTILES * KSTEPS)      // 512
#define CAP 16
#define CSTR 17
#define TILE_E 4096                // elements per 128x32 tile

typedef _Float16 f16x8 __attribute__((ext_vector_type(8)));
typedef float f32x4 __attribute__((ext_vector_type(4)));

// ===================== FAST PATH =====================

// norm + f16 hi/lo split + TILED+SWIZZLED layout:
// array[blk][ks][128x32], elem (rr,oct) stored at [rr*32 + (oct^((rr>>1)&3))*8]
__global__ void __launch_bounds__(256) norm_split_kernel(
    const float* __restrict__ q, const float* __restrict__ keys,
    _Float16* __restrict__ QhT, _Float16* __restrict__ QlT,
    _Float16* __restrict__ KhT, _Float16* __restrict__ KlT) {
  const int gw = (blockIdx.x * 256 + threadIdx.x) >> 6;
  const int lane = threadIdx.x & 63;
  const float* row; _Float16 *oh, *ol; int rr;
  if (gw < M_ROWS) {
    row = q + (size_t)gw * DKK; rr = gw & 127;
    const size_t tb = (size_t)(gw >> 7) * 16 * TILE_E;
    oh = QhT + tb; ol = QlT + tb;
  } else {
    const int n = gw - M_ROWS;
    if (n >= N_KEYS) return;
    row = keys + (size_t)n * DKK; rr = n & 127;
    const size_t tb = (size_t)(n >> 7) * 16 * TILE_E;
    oh = KhT + tb; ol = KlT + tb;
  }
  const float4 a = *(const float4*)&row[lane * 8];
  const float4 b = *(const float4*)&row[lane * 8 + 4];
  float s = a.x*a.x + a.y*a.y + a.z*a.z + a.w*a.w
          + b.x*b.x + b.y*b.y + b.z*b.z + b.w*b.w;
#pragma unroll
  for (int off = 32; off; off >>= 1) s += __shfl_xor(s, off);
  const float inv = 1.0f / fmaxf(sqrtf(s), 1e-12f);

  f16x8 h, l;
  const float e[8] = {a.x, a.y, a.z, a.w, b.x, b.y, b.z, b.w};
#pragma unroll
  for (int j = 0; j < 8; ++j) {
    const float y = e[j] * inv;
    h[j] = (_Float16)y;
    l[j] = (_Float16)(y - (float)h[j]);
  }
  const int ks = lane >> 2, oct = lane & 3;
  const int po = oct ^ ((rr >> 1) & 3);
  const size_t off = (size_t)ks * TILE_E + rr * 32 + po * 8;
  *(f16x8*)&oh[off] = h;
  *(f16x8*)&ol[off] = l;
}

__device__ __forceinline__ void insert32(float* tS, int* tI, float s, int idx) {
  const float ms = tS[31]; const int mi_ = tI[31];
  if (s < ms || (s == ms && idx > mi_)) return;
  int p = 0;
  while (p < KTOP && (tS[p] > s || (tS[p] == s && tI[p] < idx))) ++p;
  for (int qq = KTOP - 1; qq > p; --qq) { tS[qq] = tS[qq-1]; tI[qq] = tI[qq-1]; }
  tS[p] = s; tI[p] = idx;
}

__device__ __forceinline__ void gll16(const _Float16* g, _Float16* l) {
  __builtin_amdgcn_global_load_lds(
      (const __attribute__((address_space(1))) void*)g,
      (__attribute__((address_space(3))) void*)l, 16, 0, 0);
}

// INLINE-ASM LDS read: invisible to the compiler's waitcnt-insertion pass,
// so no auto "s_waitcnt vmcnt(0)" is forced before it (rule #18 / HK pattern).
__device__ __forceinline__ f16x8 ldsr128(const _Float16* p) {
  f16x8 d;
  const __attribute__((address_space(3))) _Float16* lp =
      (const __attribute__((address_space(3))) _Float16*)p;
  asm volatile("ds_read_b128 %0, %1" : "=v"(d) : "v"(lp));
  return d;
}

// stage one K-step tile set (Qh,Ql,Kh,Kl; each 8KB contiguous stream)
#define STAGE(RBS, SG, QKS) do {                                       \
  const size_t _qo = qb + (size_t)(QKS) * TILE_E;                      \
  const size_t _ko = kb0 + (size_t)(SG) * TILE_E;                      \
  gll16(QhT + _qo, &sQh[RBS][ldsA]);                                   \
  gll16(QlT + _qo, &sQl[RBS][ldsA]);                                   \
  gll16(KhT + _ko, &sKh[RBS][ldsA]);                                   \
  gll16(KlT + _ko, &sKl[RBS][ldsA]);                                   \
} while (0)

#define SB0() __builtin_amdgcn_sched_barrier(0)

// scan barrier (LDS-only drain)
#define LBAR() do {                                                    \
  SB0(); asm volatile("s_waitcnt lgkmcnt(0)" ::: "memory");            \
  SB0(); __builtin_amdgcn_s_barrier(); SB0();                          \
} while (0)

__global__ void __launch_bounds__(512, 2) gemm_topk_kernel(
    const _Float16* __restrict__ QhT, const _Float16* __restrict__ QlT,
    const _Float16* __restrict__ KhT, const _Float16* __restrict__ KlT,
    float* __restrict__ pscore, int* __restrict__ pidx) {
  __shared__ __attribute__((aligned(16))) _Float16 sQh[3][TILE_E];  // 24 KB
  __shared__ __attribute__((aligned(16))) _Float16 sQl[3][TILE_E];
  __shared__ __attribute__((aligned(16))) _Float16 sKh[3][TILE_E];
  __shared__ __attribute__((aligned(16))) _Float16 sKl[3][TILE_E];
  __shared__ float topS[BM * 33];
  __shared__ int   topI[BM * 33];
  __shared__ float candS[BM * CSTR];
  __shared__ int   candI[BM * CSTR];
  __shared__ float mS[BM];
  __shared__ int   cnt[BM];
  __shared__ int   sOver;

  const int tid  = threadIdx.x;
  const int lane = tid & 63;
  const int w    = tid >> 6;           // 8 waves
  const int wr   = w >> 1, wc = w & 1; // wave tile 32x64
  const int cl   = lane & 15;
  const int g    = lane >> 4;
  const int g4   = g * 4;

  // XCD-chunked bijective swizzle: 256 blocks = 8 XCD * 32
  const int lin   = (int)(blockIdx.x + gridDim.x * blockIdx.y);
  const int virt  = (lin & 7) * 32 + (lin >> 3);
  const int mblk  = virt & (MBLKS - 1);
  const int split = virt >> 4;
  const int qbase  = mblk * BM;
  const int nbase0 = split * NRANGE;

  const int ldsA = tid * 8;
  const size_t qb  = (size_t)mblk * 16 * TILE_E + ldsA;
  const size_t kb0 = (size_t)(split * NTILES) * 16 * TILE_E + ldsA;

  // fragment offsets (tile-image swizzle)
  int offA[2], offB[4];
#pragma unroll
  for (int mi = 0; mi < 2; ++mi) {
    const int r = wr * 32 + mi * 16 + cl;
    offA[mi] = r * 32 + (g ^ ((r >> 1) & 3)) * 8;
  }
#pragma unroll
  for (int ni = 0; ni < 4; ++ni) {
    const int c = wc * 64 + ni * 16 + cl;
    offB[ni] = c * 32 + (g ^ ((c >> 1) & 3)) * 8;
  }

  if (tid < BM) {
    mS[tid] = -INFINITY; cnt[tid] = 0;
#pragma unroll
    for (int j = 0; j < KTOP; ++j) { topS[tid*33+j] = -INFINITY; topI[tid*33+j] = 0x7fffffff; }
  }
  if (tid == 0) sOver = 0;

  // prologue: stages s=0 (buf0), s=1 (buf1) in flight (8 gll)
  STAGE(0, 0, 0);
  STAGE(1, 1, 1);

  int rb = 0;  // buffer of current step = s % 3

  for (int ct = 0; ct < NTILES; ++ct) {
    const int n0 = nbase0 + ct * BN;
    f32x4 acc[2][4];
#pragma unroll
    for (int mi = 0; mi < 2; ++mi)
#pragma unroll
      for (int ni = 0; ni < 4; ++ni) acc[mi][ni] = (f32x4)0.0f;

    for (int ks = 0; ks < KSTEPS; ++ks) {
      const int s = ct * KSTEPS + ks;
      // counted wait: oldest stage (this step's 4 gll) done; newer stay in flight
      if (s == TOT - 1) {
        SB0(); asm volatile("s_waitcnt vmcnt(0)" ::: "memory"); SB0();
      } else {
        SB0(); asm volatile("s_waitcnt vmcnt(4)" ::: "memory"); SB0();
      }
      __builtin_amdgcn_s_barrier();
      SB0();

      if (s + 2 < TOT) {
        int rb2 = rb + 2; if (rb2 >= 3) rb2 -= 3;
        STAGE(rb2, s + 2, (s + 2) & 15);
      }
      SB0();

      // fragment reads via inline asm (no compiler-inserted vmcnt drain)
      f16x8 Ah0 = ldsr128(&sQh[rb][offA[0]]);
      f16x8 Ah1 = ldsr128(&sQh[rb][offA[1]]);
      f16x8 Al0 = ldsr128(&sQl[rb][offA[0]]);
      f16x8 Al1 = ldsr128(&sQl[rb][offA[1]]);
      f16x8 Bh[4], Bl[4];
#pragma unroll
      for (int ni = 0; ni < 4; ++ni) {
        Bh[ni] = ldsr128(&sKh[rb][offB[ni]]);
        Bl[ni] = ldsr128(&sKl[rb][offB[ni]]);
      }
      asm volatile("s_waitcnt lgkmcnt(0)" ::: "memory");
      SB0();   // rule #18: pin MFMAs after the lgkmcnt

      __builtin_amdgcn_s_setprio(1);
#pragma unroll
      for (int ni = 0; ni < 4; ++ni) {
        acc[0][ni] = __builtin_amdgcn_mfma_f32_16x16x32_f16(Al0, Bh[ni], acc[0][ni], 0, 0, 0);
        acc[0][ni] = __builtin_amdgcn_mfma_f32_16x16x32_f16(Ah0, Bl[ni], acc[0][ni], 0, 0, 0);
        acc[0][ni] = __builtin_amdgcn_mfma_f32_16x16x32_f16(Ah0, Bh[ni], acc[0][ni], 0, 0, 0);
        acc[1][ni] = __builtin_amdgcn_mfma_f32_16x16x32_f16(Al1, Bh[ni], acc[1][ni], 0, 0, 0);
        acc[1][ni] = __builtin_amdgcn_mfma_f32_16x16x32_f16(Ah1, Bl[ni], acc[1][ni], 0, 0, 0);
        acc[1][ni] = __builtin_amdgcn_mfma_f32_16x16x32_f16(Ah1, Bh[ni], acc[1][ni], 0, 0, 0);
      }
      __builtin_amdgcn_s_setprio(0);

      ++rb; if (rb >= 3) rb -= 3;
    }

    // -------- candidate scan from accumulators --------
    LBAR();
    float m[2][4];
#pragma unroll
    for (int mi = 0; mi < 2; ++mi) {
      const f32x4 mv = *(const f32x4*)&mS[wr * 32 + mi * 16 + g4];
      m[mi][0] = mv[0]; m[mi][1] = mv[1]; m[mi][2] = mv[2]; m[mi][3] = mv[3];
    }
    unsigned int pend = 0u;
#pragma unroll
    for (int mi = 0; mi < 2; ++mi)
#pragma unroll
      for (int ni = 0; ni < 4; ++ni)
#pragma unroll
        for (int j = 0; j < 4; ++j)
          if (acc[mi][ni][j] >= m[mi][j])
            pend |= 1u << (mi * 16 + ni * 4 + j);

    for (;;) {
      if (pend) {
#pragma unroll
        for (int mi = 0; mi < 2; ++mi)
#pragma unroll
          for (int ni = 0; ni < 4; ++ni)
#pragma unroll
            for (int j = 0; j < 4; ++j) {
              const int bit = mi * 16 + ni * 4 + j;
              if (pend & (1u << bit)) {
                const int r = wr * 32 + mi * 16 + g4 + j;
                const int t = atomicAdd(&cnt[r], 1);
                if (t < CAP) {
                  candS[r * CSTR + t] = acc[mi][ni][j];
                  candI[r * CSTR + t] = n0 + wc * 64 + ni * 16 + cl;
                  pend &= ~(1u << bit);
                }
              }
            }
      }
      LBAR();
      if (tid < BM) {
        int nc = cnt[tid];
        if (nc > CAP) { sOver = 1; nc = CAP; }
        float* tS = &topS[tid * 33];
        int*   tI = &topI[tid * 33];
        for (int e = 0; e < nc; ++e) insert32(tS, tI, candS[tid * CSTR + e], candI[tid * CSTR + e]);
        mS[tid] = tS[KTOP - 1];
        cnt[tid] = 0;
      }
      LBAR();
      const int over = sOver;
      LBAR();
      if (tid == 0) sOver = 0;
      if (!over) break;
#pragma unroll
      for (int mi = 0; mi < 2; ++mi) {
        const f32x4 mv = *(const f32x4*)&mS[wr * 32 + mi * 16 + g4];
        m[mi][0] = mv[0]; m[mi][1] = mv[1]; m[mi][2] = mv[2]; m[mi][3] = mv[3];
      }
      unsigned int keep = 0u;
#pragma unroll
      for (int mi = 0; mi < 2; ++mi)
#pragma unroll
        for (int ni = 0; ni < 4; ++ni)
#pragma unroll
          for (int j = 0; j < 4; ++j) {
            const int bit = mi * 16 + ni * 4 + j;
            if ((pend & (1u << bit)) && acc[mi][ni][j] >= m[mi][j])
              keep |= 1u << bit;
          }
      pend = keep;
    }
  }

  if (tid < BM) {
    const size_t base = ((size_t)(qbase + tid) * NSPLIT + split) * KTOP;
    for (int j = 0; j < KTOP; ++j) {
      pscore[base + j] = topS[tid * 33 + j];
      pidx[base + j]   = topI[tid * 33 + j];
    }
  }
}

// ===================== FALLBACK (round-1, proven) =====================

#define QB 128
#define NB 128
#define KC 32
#define FNTILES (NRANGE / NB)
#define KCH (DKK / KC)
#define LDST 132

__global__ void __launch_bounds__(256) norm_kernel(
    const float* __restrict__ q, const float* __restrict__ keys,
    float* __restrict__ qn, float* __restrict__ kinv) {
  const int gw = (blockIdx.x * 256 + threadIdx.x) >> 6;
  const int lane = threadIdx.x & 63;
  if (gw < M_ROWS) {
    const float* row = q + (size_t)gw * DKK;
    float4 a = ((const float4*)row)[lane];
    float4 b = ((const float4*)row)[lane + 64];
    float s = a.x*a.x + a.y*a.y + a.z*a.z + a.w*a.w
            + b.x*b.x + b.y*b.y + b.z*b.z + b.w*b.w;
#pragma unroll
    for (int off = 32; off; off >>= 1) s += __shfl_xor(s, off);
    const float inv = 1.0f / fmaxf(sqrtf(s), 1e-12f);
    float* orow = qn + (size_t)gw * DKK;
    ((float4*)orow)[lane]      = make_float4(a.x*inv, a.y*inv, a.z*inv, a.w*inv);
    ((float4*)orow)[lane + 64] = make_float4(b.x*inv, b.y*inv, b.z*inv, b.w*inv);
  } else {
    const int n = gw - M_ROWS;
    if (n < N_KEYS) {
      const float* row = keys + (size_t)n * DKK;
      float4 a = ((const float4*)row)[lane];
      float4 b = ((const float4*)row)[lane + 64];
      float s = a.x*a.x + a.y*a.y + a.z*a.z + a.w*a.w
              + b.x*b.x + b.y*b.y + b.z*b.z + b.w*b.w;
#pragma unroll
      for (int off = 32; off; off >>= 1) s += __shfl_xor(s, off);
      if (lane == 0) kinv[n] = 1.0f / fmaxf(sqrtf(s), 1e-12f);
    }
  }
}

__device__ __forceinline__ void lds_wr_tile(float* dst, int k8, int r, float4 v, float scale) {
  dst[(k8 * 4 + 0) * LDST + r] = v.x * scale;
  dst[(k8 * 4 + 1) * LDST + r] = v.y * scale;
  dst[(k8 * 4 + 2) * LDST + r] = v.z * scale;
  dst[(k8 * 4 + 3) * LDST + r] = v.w * scale;
}

__global__ void __launch_bounds__(256, 1) score_topk_kernel(
    const float* __restrict__ qn, const float* __restrict__ keys,
    const float* __restrict__ kinv,
    float* __restrict__ pscore, int* __restrict__ pidx) {
  __shared__ float u[16896];
  __shared__ float topS[QB * KTOP];
  __shared__ int   topI[QB * KTOP];

  const int tid = threadIdx.x;
  const int tx = tid & 15, ty = tid >> 4;
  const int qbase = blockIdx.y * QB;
  const int nbase0 = blockIdx.x * NRANGE;

  for (int i = tid; i < QB * KTOP; i += 256) { topS[i] = -INFINITY; topI[i] = 0; }
  __syncthreads();

  for (int t = 0; t < FNTILES; ++t) {
    const int n0 = nbase0 + t * NB;
    float acc[8][8];
#pragma unroll
    for (int i = 0; i < 8; ++i)
#pragma unroll
      for (int j = 0; j < 8; ++j) acc[i][j] = 0.0f;

#pragma unroll
    for (int p = 0; p < 4; ++p) {
      const int id = tid + p * 256;
      const int r = id >> 3, k8 = id & 7;
      const float4 va = *(const float4*)&qn[(size_t)(qbase + r) * DKK + k8 * 4];
      const float4 vb = *(const float4*)&keys[(size_t)(n0 + r) * DKK + k8 * 4];
      const float kv = kinv[n0 + r];
      lds_wr_tile(u, k8, r, va, 1.0f);
      lds_wr_tile(u + 4224, k8, r, vb, kv);
    }
    __syncthreads();

    for (int kc = 0; kc < KCH; ++kc) {
      float4 pa[4], pb[4]; float pk[4];
      const bool pre = (kc + 1 < KCH);
      if (pre) {
#pragma unroll
        for (int p = 0; p < 4; ++p) {
          const int id = tid + p * 256;
          const int r = id >> 3, k8 = id & 7;
          pa[p] = *(const float4*)&qn[(size_t)(qbase + r) * DKK + (kc + 1) * KC + k8 * 4];
          pb[p] = *(const float4*)&keys[(size_t)(n0 + r) * DKK + (kc + 1) * KC + k8 * 4];
          pk[p] = kinv[n0 + r];
        }
      }
      const float* As = u + (kc & 1) * 8448;
      const float* Bs = As + 4224;
#pragma unroll 4
      for (int kk = 0; kk < KC; ++kk) {
        const float4 a0 = *(const float4*)&As[kk * LDST + ty * 4];
        const float4 a1 = *(const float4*)&As[kk * LDST + ty * 4 + 64];
        const float4 b0 = *(const float4*)&Bs[kk * LDST + tx * 4];
        const float4 b1 = *(const float4*)&Bs[kk * LDST + tx * 4 + 64];
        const float av[8] = {a0.x,a0.y,a0.z,a0.w,a1.x,a1.y,a1.z,a1.w};
        const float bv[8] = {b0.x,b0.y,b0.z,b0.w,b1.x,b1.y,b1.z,b1.w};
#pragma unroll
        for (int i = 0; i < 8; ++i)
#pragma unroll
          for (int j = 0; j < 8; ++j)
            acc[i][j] = fmaf(av[i], bv[j], acc[i][j]);
      }
      if (pre) {
        float* Ad = u + ((kc + 1) & 1) * 8448;
        float* Bd = Ad + 4224;
#pragma unroll
        for (int p = 0; p < 4; ++p) {
          const int id = tid + p * 256;
          const int r = id >> 3, k8 = id & 7;
          lds_wr_tile(Ad, k8, r, pa[p], 1.0f);
          lds_wr_tile(Bd, k8, r, pb[p], pk[p]);
        }
      }
      __syncthreads();
    }

#pragma unroll
    for (int ib = 0; ib < 2; ++ib)
#pragma unroll
      for (int i = 0; i < 4; ++i) {
        const int r = ty * 4 + i + ib * 64;
#pragma unroll
        for (int jb = 0; jb < 2; ++jb) {
          *(float4*)&u[r * LDST + tx * 4 + jb * 64] =
              make_float4(acc[ib*4+i][jb*4+0], acc[ib*4+i][jb*4+1],
                          acc[ib*4+i][jb*4+2], acc[ib*4+i][jb*4+3]);
        }
      }
    __syncthreads();

    if (tid < QB) {
      const int row = tid;
      float* tS = &topS[row * KTOP];
      int*   tI = &topI[row * KTOP];
      float mSv = tS[KTOP - 1]; int mIv = tI[KTOP - 1];
      for (int c4 = 0; c4 < NB / 4; ++c4) {
        const float4 v = *(const float4*)&u[row * LDST + c4 * 4];
#pragma unroll
        for (int wv = 0; wv < 4; ++wv) {
          const float s = (&v.x)[wv];
          const int idx = n0 + c4 * 4 + wv;
          if (s > mSv || (s == mSv && idx < mIv)) {
            int p = 0;
            while (p < KTOP && (tS[p] > s || (tS[p] == s && tI[p] < idx))) ++p;
            for (int qq = KTOP - 1; qq > p; --qq) { tS[qq] = tS[qq-1]; tI[qq] = tI[qq-1]; }
            tS[p] = s; tI[p] = idx;
            mSv = tS[KTOP - 1]; mIv = tI[KTOP - 1];
          }
        }
      }
    }
    __syncthreads();
  }

  if (tid < QB) {
    const size_t base = ((size_t)(qbase + tid) * NSPLIT + blockIdx.x) * KTOP;
    for (int j = 0; j < KTOP; ++j) {
      pscore[base + j] = topS[tid * KTOP + j];
      pidx[base + j]   = topI[tid * KTOP + j];
    }
  }
}

// ---------- shared: merge sorted partial lists, softmax, gather ----------
__global__ void __launch_bounds__(256) merge_kernel(
    const float* __restrict__ pscore, const int* __restrict__ pidx,
    const float* __restrict__ values,
    float* __restrict__ out_agg, float* __restrict__ out_attn, float* __restrict__ out_idx) {
  __shared__ float attn_s[KTOP];
  __shared__ int   sel_i[KTOP];
  const int row = blockIdx.x;
  const int tid = threadIdx.x;

  if (tid < 64) {
    const int lane = tid;
    const float* ps = pscore + (size_t)row * NSPLIT * KTOP;
    const int*   pi = pidx   + (size_t)row * NSPLIT * KTOP;
    int pos = 0;
    float s; int idx;
    if (lane < NSPLIT) { s = ps[lane * KTOP]; idx = pi[lane * KTOP]; }
    else { s = -INFINITY; idx = 0x7fffffff; }
    for (int it = 0; it < KTOP; ++it) {
      float wsv = s; int wi = idx; int wl = lane;
#pragma unroll
      for (int off = 32; off; off >>= 1) {
        const float os = __shfl_xor(wsv, off);
        const int   oi = __shfl_xor(wi, off);
        const int   ol = __shfl_xor(wl, off);
        if (os > wsv || (os == wsv && oi < wi)) { wsv = os; wi = oi; wl = ol; }
      }
      if (lane == 0) { attn_s[it] = wsv; sel_i[it] = wi; }
      if (lane == wl) {
        ++pos;
        if (pos < KTOP) { s = ps[lane * KTOP + pos]; idx = pi[lane * KTOP + pos]; }
        else { s = -INFINITY; idx = 0x7fffffff; }
      }
    }
  }
  __syncthreads();
  if (tid < KTOP) {
    const float mm = attn_s[0];
    const float e = expf((attn_s[tid] - mm) * 10.0f);
    float tsum = e;
#pragma unroll
    for (int off = 16; off; off >>= 1) tsum += __shfl_xor(tsum, off);
    const float a = e / tsum;
    out_attn[(size_t)row * KTOP + tid] = a;
    out_idx [(size_t)row * KTOP + tid] = (float)sel_i[tid];
    attn_s[tid] = a;
  }
  __syncthreads();

  const int d = tid * 2;
  float2 accv = make_float2(0.0f, 0.0f);
  for (int j = 0; j < KTOP; ++j) {
    const float wgt = attn_s[j];
    const float2 v = *(const float2*)&values[(size_t)sel_i[j] * DVV + d];
    accv.x = fmaf(wgt, v.x, accv.x);
    accv.y = fmaf(wgt, v.y, accv.y);
  }
  *(float2*)&out_agg[(size_t)row * DVV + d] = accv;
}

extern "C" void kernel_launch(void* const* d_in, const int* in_sizes, int n_in,
                              void* d_out, int out_size, void* d_ws, size_t ws_size,
                              hipStream_t stream) {
  const float* q      = (const float*)d_in[0];
  const float* keys   = (const float*)d_in[1];
  const float* values = (const float*)d_in[2];

  float* out      = (float*)d_out;
  float* out_agg  = out;
  float* out_attn = out + (size_t)M_ROWS * DVV;
  float* out_idx  = out_attn + (size_t)M_ROWS * KTOP;

  const size_t needFast =
      (size_t)M_ROWS * DKK * 2 * 2
    + (size_t)N_KEYS * DKK * 2 * 2
    + (size_t)M_ROWS * NSPLIT * KTOP * 8;

  if (ws_size >= needFast) {
    _Float16* QhT = (_Float16*)d_ws;
    _Float16* QlT = QhT + (size_t)M_ROWS * DKK;
    _Float16* KhT = QlT + (size_t)M_ROWS * DKK;
    _Float16* KlT = KhT + (size_t)N_KEYS * DKK;
    float* pscore = (float*)(KlT + (size_t)N_KEYS * DKK);
    int*   pidx   = (int*)(pscore + (size_t)M_ROWS * NSPLIT * KTOP);

    norm_split_kernel<<<(M_ROWS + N_KEYS) / 4, 256, 0, stream>>>(q, keys, QhT, QlT, KhT, KlT);
    dim3 g2(MBLKS, NSPLIT, 1);
    gemm_topk_kernel<<<g2, 512, 0, stream>>>(QhT, QlT, KhT, KlT, pscore, pidx);
    merge_kernel<<<M_ROWS, 256, 0, stream>>>(pscore, pidx, values, out_agg, out_attn, out_idx);
  } else {
    float* ws     = (float*)d_ws;
    float* qn     = ws;
    float* kinv   = qn + (size_t)M_ROWS * DKK;
    float* pscore = kinv + N_KEYS;
    int*   pidx   = (int*)(pscore + (size_t)M_ROWS * NSPLIT * KTOP);

    norm_kernel<<<(M_ROWS + N_KEYS) / 4, 256, 0, stream>>>(q, keys, qn, kinv);
    dim3 g2(NSPLIT, M_ROWS / QB, 1);
    score_topk_kernel<<<g2, 256, 0, stream>>>(qn, keys, kinv, pscore, pidx);
    merge_kernel<<<M_ROWS, 256, 0, stream>>>(pscore, pidx, values, out_agg, out_attn, out_idx);
  }
}